// Round 3
// baseline (401.376 us; speedup 1.0000x reference)
//
#include <hip/hip_runtime.h>
#include <hip/hip_bf16.h>
#include <math.h>

#define NTOK 131072
#define DIM  256
#define EDIM 512
#define NB   16
#define NL   64
#define NSEG (NB*NL)    // 1024
#define K3D  768        // 3*DIM
#define K2D  512        // 2*DIM
#define HB   64         // histogram/scatter blocks (2048 tokens each)

typedef __attribute__((ext_vector_type(8))) short short8;
typedef __attribute__((ext_vector_type(4))) float f32x4;

// monotone float<->uint code so atomicMax(uint) == float max
static __device__ __forceinline__ unsigned fcode(float x){
  unsigned b = __float_as_uint(x);
  return (b & 0x80000000u) ? ~b : (b | 0x80000000u);
}
static __device__ __forceinline__ float fdecode(unsigned c){
  unsigned b = (c & 0x80000000u) ? (c ^ 0x80000000u) : ~c;
  return __uint_as_float(b);
}
#define NEG_INF_CODE 0x007FFFFFu   // fcode(-inf)

static __device__ __forceinline__ short f2bf(float x){
  union { __hip_bfloat16 h; short s; } u; u.h = __float2bfloat16(x); return u.s;
}

// ---------------- K0t: transpose+convert weights to bf16 [N][K]; also init bmax ----------------
__global__ __launch_bounds__(256) void k0_transpose(const float* __restrict__ W1, const float* __restrict__ W2,
                                                    const float* __restrict__ Wc,
                                                    short* __restrict__ W1t, short* __restrict__ W2t,
                                                    short* __restrict__ Wct, unsigned* __restrict__ bmax){
  if (blockIdx.x == 0 && threadIdx.x < NB) bmax[threadIdx.x] = NEG_INF_CODE;
  __shared__ short tile[64][65];
  int b = blockIdx.x;
  const float* src; short* dst; int K, N, kt, nt;
  if (b < 96){ src=W1; dst=W1t; K=768; N=512; kt=b/8;  nt=b%8;  }
  else if (b < 128){ int c=b-96;  src=W2; dst=W2t; K=512; N=256; kt=c/4; nt=c%4; }
  else             { int c=b-128; src=Wc; dst=Wct; K=512; N=256; kt=c/4; nt=c%4; }
  int k0 = kt*64, n0 = nt*64;
  for (int e = threadIdx.x; e < 4096; e += 256){
    int r = e >> 6, c = e & 63;                       // r: k-row, c: n-col (coalesced read)
    tile[c][r] = f2bf(src[(size_t)(k0+r)*N + n0 + c]);
  }
  __syncthreads();
  for (int e = threadIdx.x; e < 4096; e += 256){
    int r = e >> 6, c = e & 63;                       // r: n-row, c: k-col (coalesced write)
    dst[(size_t)(n0+r)*K + k0 + c] = tile[r][c];
  }
}

// ---------------- K1: logits, seg ids, per-batch max ----------------
// 16-lane groups: 4 tokens in flight per wave, 8 tokens per group, full unroll for ILP.
__global__ __launch_bounds__(256) void k1_logits(const float* __restrict__ feats, const int* __restrict__ cu,
    const int* __restrict__ layer_ids, const float* __restrict__ Wa, const float* __restrict__ ba,
    float* __restrict__ logits, int* __restrict__ seg, unsigned* __restrict__ bmax){
  int tid = threadIdx.x;
  int wave = tid >> 6, lane = tid & 63;
  int g = lane >> 4, s = lane & 15;
  int tbase = blockIdx.x*128 + wave*32 + g*8;
  float4 wa[4];
#pragma unroll
  for (int it = 0; it < 4; ++it) wa[it] = *(const float4*)(Wa + it*64 + s*4);
  float bav = ba[0];
  int cub = cu[s+1];
  unsigned long long gshift = (unsigned long long)(g*16);
  float wmax = -INFINITY; int wbatch = -1;
#pragma unroll
  for (int k = 0; k < 8; ++k){
    int t = tbase + k;
    const float* fp = feats + (size_t)t*DIM + s*4;
    float p = 0.f;
#pragma unroll
    for (int it = 0; it < 4; ++it){
      float4 x = *(const float4*)(fp + it*64);
      p += x.x*wa[it].x + x.y*wa[it].y + x.z*wa[it].z + x.w*wa[it].w;
    }
#pragma unroll
    for (int off = 1; off < 16; off <<= 1) p += __shfl_xor(p, off);
    unsigned long long m = __ballot(cub <= t);
    int b = (int)__popcll((m >> gshift) & 0xFFFFull);
    if (s == 0){
      float lg = p + bav;
      logits[t] = lg;
      seg[t] = b*NL + layer_ids[t];
      if (b != wbatch){
        if (wbatch >= 0) atomicMax(&bmax[wbatch], fcode(wmax));
        wbatch = b; wmax = lg;
      } else wmax = fmaxf(wmax, lg);
    }
  }
  if (s == 0 && wbatch >= 0) atomicMax(&bmax[wbatch], fcode(wmax));
}

// ---------------- K2: exp + per-batch Z (deterministic tree) ----------------
__global__ __launch_bounds__(256) void k2_softmax_z(const float* __restrict__ logits, const int* __restrict__ cu,
    const unsigned* __restrict__ bmax, float* __restrict__ evals, float* __restrict__ bz){
  __shared__ float red[256];
  int b = blockIdx.x;
  int s = cu[b], e = cu[b+1];
  float m = fdecode(bmax[b]);
  float acc = 0.f;
  for (int i = s + threadIdx.x; i < e; i += 256){
    float ev = expf(logits[i] - m);
    evals[i] = ev; acc += ev;
  }
  red[threadIdx.x] = acc; __syncthreads();
  for (int off = 128; off; off >>= 1){
    if (threadIdx.x < off) red[threadIdx.x] += red[threadIdx.x + off];
    __syncthreads();
  }
  if (threadIdx.x == 0) bz[b] = red[0];
}

// ---------------- K3a: per-block segment histogram ----------------
__global__ __launch_bounds__(256) void k3a_hist(const int* __restrict__ seg, int* __restrict__ hist){
  __shared__ int h[NSEG];
  for (int i = threadIdx.x; i < NSEG; i += 256) h[i] = 0;
  __syncthreads();
  int base = blockIdx.x * (NTOK/HB);
  for (int i = threadIdx.x; i < NTOK/HB; i += 256) atomicAdd(&h[seg[base+i]], 1);
  __syncthreads();
  for (int i = threadIdx.x; i < NSEG; i += 256) hist[i*HB + blockIdx.x] = h[i];
}

// ---------------- K3b: scan -> per-(seg,block) offsets + segstart ----------------
__global__ __launch_bounds__(1024) void k3b_scan(int* __restrict__ hist, int* __restrict__ segstart){
  __shared__ int sc[NSEG];
  int s = threadIdx.x;
  int base = s*HB;
  int tot = 0;
#pragma unroll
  for (int b = 0; b < HB; ++b) tot += hist[base+b];
  sc[s] = tot; __syncthreads();
  for (int off = 1; off < NSEG; off <<= 1){
    int v = (s >= off) ? sc[s-off] : 0;
    __syncthreads();
    sc[s] += v;
    __syncthreads();
  }
  int segbase = sc[s] - tot;   // exclusive prefix
  segstart[s] = segbase;
  if (s == 0) segstart[NSEG] = NTOK;
  int run = segbase;
#pragma unroll
  for (int b = 0; b < HB; ++b){ int c = hist[base+b]; hist[base+b] = run; run += c; }
}

// ---------------- K3c: stable-ish scatter of token ids by segment ----------------
__global__ __launch_bounds__(256) void k3c_scatter(const int* __restrict__ seg, const int* __restrict__ hist,
                                                   int* __restrict__ sorted){
  __shared__ int cur[NSEG];
  for (int i = threadIdx.x; i < NSEG; i += 256) cur[i] = hist[i*HB + blockIdx.x];
  __syncthreads();
  int base = blockIdx.x * (NTOK/HB);
  for (int i = threadIdx.x; i < NTOK/HB; i += 256){
    int sg = seg[base+i];
    int p = atomicAdd(&cur[sg], 1);
    sorted[p] = base+i;
  }
}

// ---------------- K4: segmented reduce over sorted tokens -> pooled [1024][768] bf16 ----------------
__global__ __launch_bounds__(256) void k4_pool(const float* __restrict__ feats, const int* __restrict__ sorted,
    const int* __restrict__ segstart, const float* __restrict__ evals, const float* __restrict__ bz,
    short* __restrict__ pooledb){
  __shared__ float redS[4][DIM];
  __shared__ float redM[4][DIM];
  __shared__ float redA[4][DIM];
  int sgi = blockIdx.x;
  int b = sgi >> 6;
  int s = segstart[sgi], e = segstart[sgi+1];
  int cnt = e - s;
  float invz = 1.0f / bz[b];
  int lane = threadIdx.x & 63, grp = threadIdx.x >> 6;
  float4 sum = make_float4(0.f,0.f,0.f,0.f), att = make_float4(0.f,0.f,0.f,0.f);
  float4 mx  = make_float4(-INFINITY,-INFINITY,-INFINITY,-INFINITY);
  for (int i = s + grp; i < e; i += 4){
    int tok = sorted[i];
    float4 x = *(const float4*)(feats + (size_t)tok*DIM + lane*4);
    float w = evals[tok] * invz;
    sum.x += x.x; sum.y += x.y; sum.z += x.z; sum.w += x.w;
    mx.x = fmaxf(mx.x, x.x); mx.y = fmaxf(mx.y, x.y);
    mx.z = fmaxf(mx.z, x.z); mx.w = fmaxf(mx.w, x.w);
    att.x += x.x*w; att.y += x.y*w; att.z += x.z*w; att.w += x.w*w;
  }
  *(float4*)&redS[grp][lane*4] = sum;
  *(float4*)&redM[grp][lane*4] = mx;
  *(float4*)&redA[grp][lane*4] = att;
  __syncthreads();
  int d = threadIdx.x;
  float rs = redS[0][d] + redS[1][d] + redS[2][d] + redS[3][d];
  float rm = fmaxf(fmaxf(redM[0][d], redM[1][d]), fmaxf(redM[2][d], redM[3][d]));
  float ra = redA[0][d] + redA[1][d] + redA[2][d] + redA[3][d];
  float inv = 1.0f / (float)(cnt > 1 ? cnt : 1);
  size_t rb_ = (size_t)sgi * K3D;
  pooledb[rb_ + d]         = f2bf(rs * inv);
  pooledb[rb_ + DIM + d]   = f2bf(cnt > 0 ? rm : 0.f);
  pooledb[rb_ + 2*DIM + d] = f2bf(ra);
}

// ---------------- small MFMA GEMM: C[M,N] = act(A[M,K] @ Bt[N,K]^T + bias) -> bf16 ----------------
template<int GELU>
__global__ __launch_bounds__(256) void gemm64(const short* __restrict__ A, const short* __restrict__ Bt,
    const float* __restrict__ bias, short* __restrict__ Cout, int K, int ldc){
  __shared__ short lA[64][40];
  __shared__ short lB[64][40];
  int tid = threadIdx.x;
  int wave = tid >> 6, lane = tid & 63;
  int wm = wave >> 1, wn = wave & 1;
  int rb = blockIdx.x * 64, cb = blockIdx.y * 64;
  int l15 = lane & 15, lg = lane >> 4;
  f32x4 acc[2][2] = {};
  int srow = tid >> 2, skg = tid & 3;
  for (int ks = 0; ks < K; ks += 32){
    __syncthreads();
    *(short8*)&lA[srow][skg*8] = *(const short8*)(A  + (size_t)(rb+srow)*K + ks + skg*8);
    *(short8*)&lB[srow][skg*8] = *(const short8*)(Bt + (size_t)(cb+srow)*K + ks + skg*8);
    __syncthreads();
    short8 af[2], bf[2];
#pragma unroll
    for (int f = 0; f < 2; ++f){
      af[f] = *(const short8*)&lA[wm*32 + f*16 + l15][lg*8];
      bf[f] = *(const short8*)&lB[wn*32 + f*16 + l15][lg*8];
    }
#pragma unroll
    for (int fm = 0; fm < 2; ++fm)
#pragma unroll
      for (int fn = 0; fn < 2; ++fn)
        acc[fm][fn] = __builtin_amdgcn_mfma_f32_16x16x32_bf16(af[fm], bf[fn], acc[fm][fn], 0, 0, 0);
  }
#pragma unroll
  for (int fm = 0; fm < 2; ++fm)
#pragma unroll
    for (int fn = 0; fn < 2; ++fn){
      int col = cb + wn*32 + fn*16 + l15;
      float bcv = bias[col];
#pragma unroll
      for (int r = 0; r < 4; ++r){
        int row = rb + wm*32 + fm*16 + lg*4 + r;
        float v = acc[fm][fn][r] + bcv;
        if (GELU) v = 0.5f * v * (1.0f + erff(v * 0.70710678118f));
        Cout[(size_t)row*ldc + col] = f2bf(v);
      }
    }
}

// ---------------- K5: out = [gather(lf, seg) | feats] @ Wc + bc ----------------
// block: 128 rows x 256 cols (full N), 8 waves (2x4), wave tile 64x64 = 4x4 frags
__global__ __launch_bounds__(512) void k5_final(const float* __restrict__ feats, const short* __restrict__ lfb,
    const int* __restrict__ seg, const short* __restrict__ Wct, const float* __restrict__ bc,
    float* __restrict__ out){
  __shared__ short lA[128][72];
  __shared__ short lB[256][72];
  int tid = threadIdx.x;
  int wave = tid >> 6, lane = tid & 63;
  int wm = wave >> 2, wn = wave & 3;
  int rb = blockIdx.x * 128;
  int l15 = lane & 15, lg = lane >> 4;
  // each thread stages 2 fixed A-rows across all ks: hoist the seg gather
  int row0 = tid >> 3,       kg0 = tid & 7;
  int row1 = (tid+512) >> 3, kg1 = tid & 7;
  const short* lfb0 = lfb + (size_t)seg[rb + row0]*DIM;
  const short* lfb1 = lfb + (size_t)seg[rb + row1]*DIM;
  f32x4 acc[4][4] = {};
  for (int ks = 0; ks < 8; ++ks){
    __syncthreads();
    // stage A: 128 rows x 64 k (bf16). k<256 -> gathered layer_feats; k>=256 -> feats (f32->bf16)
#pragma unroll
    for (int i = 0; i < 2; ++i){
      int row = i ? row1 : row0;
      int kg  = i ? kg1  : kg0;
      short8 v;
      if (ks < 4){
        const short* src = (i ? lfb1 : lfb0) + ks*64 + kg*8;
        v = *(const short8*)src;
      } else {
        const float* fp = feats + (size_t)(rb+row)*DIM + (ks-4)*64 + kg*8;
        float4 u0 = *(const float4*)fp;
        float4 u1 = *(const float4*)(fp+4);
        short8 t;
        t[0]=f2bf(u0.x); t[1]=f2bf(u0.y); t[2]=f2bf(u0.z); t[3]=f2bf(u0.w);
        t[4]=f2bf(u1.x); t[5]=f2bf(u1.y); t[6]=f2bf(u1.z); t[7]=f2bf(u1.w);
        v = t;
      }
      *(short8*)&lA[row][kg*8] = v;
    }
    // stage B: 256 n-rows x 64 k from Wct [256][512]
#pragma unroll
    for (int i = 0; i < 4; ++i){
      int slot = tid + i*512;
      int n = slot >> 3, kg = slot & 7;
      *(short8*)&lB[n][kg*8] = *(const short8*)(Wct + (size_t)n*K2D + ks*64 + kg*8);
    }
    __syncthreads();
#pragma unroll
    for (int kk = 0; kk < 2; ++kk){
      short8 af[4], bf[4];
#pragma unroll
      for (int f = 0; f < 4; ++f){
        af[f] = *(const short8*)&lA[wm*64 + f*16 + l15][kk*32 + lg*8];
        bf[f] = *(const short8*)&lB[wn*64 + f*16 + l15][kk*32 + lg*8];
      }
#pragma unroll
      for (int fm = 0; fm < 4; ++fm)
#pragma unroll
        for (int fn = 0; fn < 4; ++fn)
          acc[fm][fn] = __builtin_amdgcn_mfma_f32_16x16x32_bf16(af[fm], bf[fn], acc[fm][fn], 0, 0, 0);
    }
  }
#pragma unroll
  for (int fm = 0; fm < 4; ++fm)
#pragma unroll
    for (int fn = 0; fn < 4; ++fn){
      int col = wn*64 + fn*16 + l15;
      float bcv = bc[col];
#pragma unroll
      for (int r = 0; r < 4; ++r){
        int row = rb + wm*64 + fm*16 + lg*4 + r;
        out[(size_t)row*DIM + col] = acc[fm][fn][r] + bcv;
      }
    }
}

extern "C" void kernel_launch(void* const* d_in, const int* in_sizes, int n_in,
                              void* d_out, int out_size, void* d_ws, size_t ws_size,
                              hipStream_t stream){
  const float* feats     = (const float*)d_in[0];
  const int*   cu        = (const int*)d_in[1];
  const int*   layer_ids = (const int*)d_in[2];
  const float* Wa        = (const float*)d_in[3];
  const float* ba        = (const float*)d_in[4];
  const float* W1        = (const float*)d_in[5];
  const float* b1        = (const float*)d_in[6];
  const float* W2        = (const float*)d_in[7];
  const float* b2        = (const float*)d_in[8];
  const float* Wc        = (const float*)d_in[9];
  const float* bc        = (const float*)d_in[10];
  float* out = (float*)d_out;

  char* w = (char*)d_ws;
  auto alloc = [&](size_t bytes)->char*{ char* p = w; w += (bytes + 255) & ~255ull; return p; };
  float*    logits  = (float*)   alloc((size_t)NTOK*4);
  float*    evals   = (float*)   alloc((size_t)NTOK*4);
  int*      seg     = (int*)     alloc((size_t)NTOK*4);
  int*      sorted  = (int*)     alloc((size_t)NTOK*4);
  int*      hist    = (int*)     alloc((size_t)NSEG*HB*4);
  int*      segstart= (int*)     alloc((size_t)(NSEG+1)*4);
  unsigned* bmax    = (unsigned*)alloc(NB*4);
  float*    bz      = (float*)   alloc(NB*4);
  short*    W1t     = (short*)   alloc((size_t)512*768*2);
  short*    W2t     = (short*)   alloc((size_t)256*512*2);
  short*    Wct     = (short*)   alloc((size_t)256*512*2);
  short*    pooledb = (short*)   alloc((size_t)NSEG*K3D*2);
  short*    hb      = (short*)   alloc((size_t)NSEG*EDIM*2);
  short*    lfb     = (short*)   alloc((size_t)NSEG*DIM*2);

  k0_transpose<<<dim3(160), dim3(256), 0, stream>>>(W1, W2, Wc, W1t, W2t, Wct, bmax);
  k1_logits<<<dim3(1024), dim3(256), 0, stream>>>(feats, cu, layer_ids, Wa, ba, logits, seg, bmax);
  k2_softmax_z<<<dim3(16), dim3(256), 0, stream>>>(logits, cu, bmax, evals, bz);
  k3a_hist<<<dim3(HB), dim3(256), 0, stream>>>(seg, hist);
  k3b_scan<<<dim3(1), dim3(1024), 0, stream>>>(hist, segstart);
  k3c_scatter<<<dim3(HB), dim3(256), 0, stream>>>(seg, hist, sorted);
  k4_pool<<<dim3(NSEG), dim3(256), 0, stream>>>(feats, sorted, segstart, evals, bz, pooledb);
  gemm64<1><<<dim3(16, 8), dim3(256), 0, stream>>>(pooledb, W1t, b1, hb, 768, 512);
  gemm64<0><<<dim3(16, 4), dim3(256), 0, stream>>>(hb, W2t, b2, lfb, 512, 256);
  k5_final<<<dim3(1024), dim3(512), 0, stream>>>(feats, lfb, seg, Wct, bc, out);
}

// Round 4
// 235.228 us; speedup vs baseline: 1.7063x; 1.7063x over previous
//
#include <hip/hip_runtime.h>
#include <hip/hip_bf16.h>
#include <math.h>

#define NTOK 131072
#define DIM  256
#define EDIM 512
#define NB   16
#define NL   64
#define NSEG (NB*NL)    // 1024
#define K3D  768        // 3*DIM
#define K2D  512        // 2*DIM
#define HB   64         // histogram/scatter blocks (2048 tokens each)

typedef __attribute__((ext_vector_type(8))) short short8;
typedef __attribute__((ext_vector_type(4))) float f32x4;

// monotone float<->uint code so atomicMax(uint) == float max
static __device__ __forceinline__ unsigned fcode(float x){
  unsigned b = __float_as_uint(x);
  return (b & 0x80000000u) ? ~b : (b | 0x80000000u);
}
static __device__ __forceinline__ float fdecode(unsigned c){
  unsigned b = (c & 0x80000000u) ? (c ^ 0x80000000u) : ~c;
  return __uint_as_float(b);
}
#define NEG_INF_CODE 0x007FFFFFu   // fcode(-inf)

static __device__ __forceinline__ short f2bf(float x){
  union { __hip_bfloat16 h; short s; } u; u.h = __float2bfloat16(x); return u.s;
}

// ---------------- K0t: transpose+convert weights to bf16 [N][K]; also init bmax ----------------
__global__ __launch_bounds__(256) void k0_transpose(const float* __restrict__ W1, const float* __restrict__ W2,
                                                    const float* __restrict__ Wc,
                                                    short* __restrict__ W1t, short* __restrict__ W2t,
                                                    short* __restrict__ Wct, unsigned* __restrict__ bmax){
  if (blockIdx.x == 0 && threadIdx.x < NB) bmax[threadIdx.x] = NEG_INF_CODE;
  __shared__ short tile[64][65];
  int b = blockIdx.x;
  const float* src; short* dst; int K, N, kt, nt;
  if (b < 96){ src=W1; dst=W1t; K=768; N=512; kt=b/8;  nt=b%8;  }
  else if (b < 128){ int c=b-96;  src=W2; dst=W2t; K=512; N=256; kt=c/4; nt=c%4; }
  else             { int c=b-128; src=Wc; dst=Wct; K=512; N=256; kt=c/4; nt=c%4; }
  int k0 = kt*64, n0 = nt*64;
  for (int e = threadIdx.x; e < 4096; e += 256){
    int r = e >> 6, c = e & 63;                       // r: k-row, c: n-col (coalesced read)
    tile[c][r] = f2bf(src[(size_t)(k0+r)*N + n0 + c]);
  }
  __syncthreads();
  for (int e = threadIdx.x; e < 4096; e += 256){
    int r = e >> 6, c = e & 63;                       // r: n-row, c: k-col (coalesced write)
    dst[(size_t)(n0+r)*K + k0 + c] = tile[r][c];
  }
}

// ---------------- K1: logits, seg ids, per-batch max ----------------
// One thread per token row (GEMV). No cross-lane ops in the hot loop: 64 independent
// float4 loads into 4 parallel accumulators; Wa broadcast from LDS.
__global__ __launch_bounds__(256) void k1_logits(const float* __restrict__ feats, const int* __restrict__ cu,
    const int* __restrict__ layer_ids, const float* __restrict__ Wa, const float* __restrict__ ba,
    float* __restrict__ logits, int* __restrict__ seg, unsigned* __restrict__ bmax){
  __shared__ float4   lwa[64];
  __shared__ int      lcu[NB];
  __shared__ unsigned lbm[NB];
  int tid = threadIdx.x;
  if (tid < 64)  lwa[tid] = *(const float4*)(Wa + tid*4);
  if (tid < NB)  lcu[tid] = cu[tid+1];
  if (tid < NB)  lbm[tid] = NEG_INF_CODE;
  __syncthreads();
  int t = blockIdx.x*256 + tid;
  const float4* fp = (const float4*)(feats + (size_t)t*DIM);
  float a0=0.f, a1=0.f, a2=0.f, a3=0.f;
#pragma unroll
  for (int i = 0; i < 16; ++i){
    float4 x0 = fp[i*4+0], x1 = fp[i*4+1], x2 = fp[i*4+2], x3 = fp[i*4+3];
    float4 w0 = lwa[i*4+0], w1 = lwa[i*4+1], w2 = lwa[i*4+2], w3 = lwa[i*4+3];
    a0 += x0.x*w0.x + x0.y*w0.y + x0.z*w0.z + x0.w*w0.w;
    a1 += x1.x*w1.x + x1.y*w1.y + x1.z*w1.z + x1.w*w1.w;
    a2 += x2.x*w2.x + x2.y*w2.y + x2.z*w2.z + x2.w*w2.w;
    a3 += x3.x*w3.x + x3.y*w3.y + x3.z*w3.z + x3.w*w3.w;
  }
  float lg = (a0+a1) + (a2+a3) + ba[0];
  int b = 0;
#pragma unroll
  for (int j = 0; j < NB-1; ++j) b += (lcu[j] <= t) ? 1 : 0;
  logits[t] = lg;
  seg[t] = b*NL + layer_ids[t];
  atomicMax(&lbm[b], fcode(lg));
  __syncthreads();
  if (tid < NB && lbm[tid] != NEG_INF_CODE) atomicMax(&bmax[tid], lbm[tid]);
}

// ---------------- K2: exp + per-batch Z (deterministic tree) ----------------
__global__ __launch_bounds__(256) void k2_softmax_z(const float* __restrict__ logits, const int* __restrict__ cu,
    const unsigned* __restrict__ bmax, float* __restrict__ evals, float* __restrict__ bz){
  __shared__ float red[256];
  int b = blockIdx.x;
  int s = cu[b], e = cu[b+1];
  float m = fdecode(bmax[b]);
  float acc = 0.f;
  for (int i = s + threadIdx.x; i < e; i += 256){
    float ev = expf(logits[i] - m);
    evals[i] = ev; acc += ev;
  }
  red[threadIdx.x] = acc; __syncthreads();
  for (int off = 128; off; off >>= 1){
    if (threadIdx.x < off) red[threadIdx.x] += red[threadIdx.x + off];
    __syncthreads();
  }
  if (threadIdx.x == 0) bz[b] = red[0];
}

// ---------------- K3a: per-block segment histogram ----------------
__global__ __launch_bounds__(256) void k3a_hist(const int* __restrict__ seg, int* __restrict__ hist){
  __shared__ int h[NSEG];
  for (int i = threadIdx.x; i < NSEG; i += 256) h[i] = 0;
  __syncthreads();
  int base = blockIdx.x * (NTOK/HB);
  for (int i = threadIdx.x; i < NTOK/HB; i += 256) atomicAdd(&h[seg[base+i]], 1);
  __syncthreads();
  for (int i = threadIdx.x; i < NSEG; i += 256) hist[i*HB + blockIdx.x] = h[i];
}

// ---------------- K3b: scan -> per-(seg,block) offsets + segstart ----------------
__global__ __launch_bounds__(1024) void k3b_scan(int* __restrict__ hist, int* __restrict__ segstart){
  __shared__ int sc[NSEG];
  int s = threadIdx.x;
  int base = s*HB;
  int tot = 0;
#pragma unroll
  for (int b = 0; b < HB; ++b) tot += hist[base+b];
  sc[s] = tot; __syncthreads();
  for (int off = 1; off < NSEG; off <<= 1){
    int v = (s >= off) ? sc[s-off] : 0;
    __syncthreads();
    sc[s] += v;
    __syncthreads();
  }
  int segbase = sc[s] - tot;   // exclusive prefix
  segstart[s] = segbase;
  if (s == 0) segstart[NSEG] = NTOK;
  int run = segbase;
#pragma unroll
  for (int b = 0; b < HB; ++b){ int c = hist[base+b]; hist[base+b] = run; run += c; }
}

// ---------------- K3c: stable-ish scatter of token ids by segment ----------------
__global__ __launch_bounds__(256) void k3c_scatter(const int* __restrict__ seg, const int* __restrict__ hist,
                                                   int* __restrict__ sorted){
  __shared__ int cur[NSEG];
  for (int i = threadIdx.x; i < NSEG; i += 256) cur[i] = hist[i*HB + blockIdx.x];
  __syncthreads();
  int base = blockIdx.x * (NTOK/HB);
  for (int i = threadIdx.x; i < NTOK/HB; i += 256){
    int sg = seg[base+i];
    int p = atomicAdd(&cur[sg], 1);
    sorted[p] = base+i;
  }
}

// ---------------- K4: segmented reduce over sorted tokens -> pooled [1024][768] bf16 ----------------
__global__ __launch_bounds__(256) void k4_pool(const float* __restrict__ feats, const int* __restrict__ sorted,
    const int* __restrict__ segstart, const float* __restrict__ evals, const float* __restrict__ bz,
    short* __restrict__ pooledb){
  __shared__ float redS[4][DIM];
  __shared__ float redM[4][DIM];
  __shared__ float redA[4][DIM];
  int sgi = blockIdx.x;
  int b = sgi >> 6;
  int s = segstart[sgi], e = segstart[sgi+1];
  int cnt = e - s;
  float invz = 1.0f / bz[b];
  int lane = threadIdx.x & 63, grp = threadIdx.x >> 6;
  float4 sum = make_float4(0.f,0.f,0.f,0.f), att = make_float4(0.f,0.f,0.f,0.f);
  float4 mx  = make_float4(-INFINITY,-INFINITY,-INFINITY,-INFINITY);
  for (int i = s + grp; i < e; i += 4){
    int tok = sorted[i];
    float4 x = *(const float4*)(feats + (size_t)tok*DIM + lane*4);
    float w = evals[tok] * invz;
    sum.x += x.x; sum.y += x.y; sum.z += x.z; sum.w += x.w;
    mx.x = fmaxf(mx.x, x.x); mx.y = fmaxf(mx.y, x.y);
    mx.z = fmaxf(mx.z, x.z); mx.w = fmaxf(mx.w, x.w);
    att.x += x.x*w; att.y += x.y*w; att.z += x.z*w; att.w += x.w*w;
  }
  *(float4*)&redS[grp][lane*4] = sum;
  *(float4*)&redM[grp][lane*4] = mx;
  *(float4*)&redA[grp][lane*4] = att;
  __syncthreads();
  int d = threadIdx.x;
  float rs = redS[0][d] + redS[1][d] + redS[2][d] + redS[3][d];
  float rm = fmaxf(fmaxf(redM[0][d], redM[1][d]), fmaxf(redM[2][d], redM[3][d]));
  float ra = redA[0][d] + redA[1][d] + redA[2][d] + redA[3][d];
  float inv = 1.0f / (float)(cnt > 1 ? cnt : 1);
  size_t rb_ = (size_t)sgi * K3D;
  pooledb[rb_ + d]         = f2bf(rs * inv);
  pooledb[rb_ + DIM + d]   = f2bf(cnt > 0 ? rm : 0.f);
  pooledb[rb_ + 2*DIM + d] = f2bf(ra);
}

// ---------------- small MFMA GEMM: C[M,N] = act(A[M,K] @ Bt[N,K]^T + bias) -> bf16 ----------------
template<int GELU>
__global__ __launch_bounds__(256) void gemm64(const short* __restrict__ A, const short* __restrict__ Bt,
    const float* __restrict__ bias, short* __restrict__ Cout, int K, int ldc){
  __shared__ short lA[64][40];
  __shared__ short lB[64][40];
  int tid = threadIdx.x;
  int wave = tid >> 6, lane = tid & 63;
  int wm = wave >> 1, wn = wave & 1;
  int rb = blockIdx.x * 64, cb = blockIdx.y * 64;
  int l15 = lane & 15, lg = lane >> 4;
  f32x4 acc[2][2] = {};
  int srow = tid >> 2, skg = tid & 3;
  for (int ks = 0; ks < K; ks += 32){
    __syncthreads();
    *(short8*)&lA[srow][skg*8] = *(const short8*)(A  + (size_t)(rb+srow)*K + ks + skg*8);
    *(short8*)&lB[srow][skg*8] = *(const short8*)(Bt + (size_t)(cb+srow)*K + ks + skg*8);
    __syncthreads();
    short8 af[2], bf[2];
#pragma unroll
    for (int f = 0; f < 2; ++f){
      af[f] = *(const short8*)&lA[wm*32 + f*16 + l15][lg*8];
      bf[f] = *(const short8*)&lB[wn*32 + f*16 + l15][lg*8];
    }
#pragma unroll
    for (int fm = 0; fm < 2; ++fm)
#pragma unroll
      for (int fn = 0; fn < 2; ++fn)
        acc[fm][fn] = __builtin_amdgcn_mfma_f32_16x16x32_bf16(af[fm], bf[fn], acc[fm][fn], 0, 0, 0);
  }
#pragma unroll
  for (int fm = 0; fm < 2; ++fm)
#pragma unroll
    for (int fn = 0; fn < 2; ++fn){
      int col = cb + wn*32 + fn*16 + l15;
      float bcv = bias[col];
#pragma unroll
      for (int r = 0; r < 4; ++r){
        int row = rb + wm*32 + fm*16 + lg*4 + r;
        float v = acc[fm][fn][r] + bcv;
        if (GELU) v = 0.5f * v * (1.0f + erff(v * 0.70710678118f));
        Cout[(size_t)row*ldc + col] = f2bf(v);
      }
    }
}

// ---------------- K5: out = [gather(lf, seg) | feats] @ Wc + bc ----------------
// block: 128 rows x 256 cols (full N), 8 waves (2x4), wave tile 64x64 = 4x4 frags
// XCD-aware block swizzle (1024 % 8 == 0 -> bijective)
__global__ __launch_bounds__(512) void k5_final(const float* __restrict__ feats, const short* __restrict__ lfb,
    const int* __restrict__ seg, const short* __restrict__ Wct, const float* __restrict__ bc,
    float* __restrict__ out){
  __shared__ short lA[128][72];
  __shared__ short lB[256][72];
  int tid = threadIdx.x;
  int wave = tid >> 6, lane = tid & 63;
  int wm = wave >> 2, wn = wave & 3;
  int bid = (int)blockIdx.x;
  int swz = (bid & 7) * 128 + (bid >> 3);
  int rb = swz * 128;
  int l15 = lane & 15, lg = lane >> 4;
  // each thread stages 2 fixed A-rows across all ks: hoist the seg gather
  int row0 = tid >> 3,       kg0 = tid & 7;
  int row1 = (tid+512) >> 3, kg1 = tid & 7;
  const short* lfb0 = lfb + (size_t)seg[rb + row0]*DIM;
  const short* lfb1 = lfb + (size_t)seg[rb + row1]*DIM;
  f32x4 acc[4][4] = {};
  for (int ks = 0; ks < 8; ++ks){
    __syncthreads();
    // stage A: 128 rows x 64 k (bf16). k<256 -> gathered layer_feats; k>=256 -> feats (f32->bf16)
#pragma unroll
    for (int i = 0; i < 2; ++i){
      int row = i ? row1 : row0;
      int kg  = i ? kg1  : kg0;
      short8 v;
      if (ks < 4){
        const short* src = (i ? lfb1 : lfb0) + ks*64 + kg*8;
        v = *(const short8*)src;
      } else {
        const float* fp = feats + (size_t)(rb+row)*DIM + (ks-4)*64 + kg*8;
        float4 u0 = *(const float4*)fp;
        float4 u1 = *(const float4*)(fp+4);
        short8 t;
        t[0]=f2bf(u0.x); t[1]=f2bf(u0.y); t[2]=f2bf(u0.z); t[3]=f2bf(u0.w);
        t[4]=f2bf(u1.x); t[5]=f2bf(u1.y); t[6]=f2bf(u1.z); t[7]=f2bf(u1.w);
        v = t;
      }
      *(short8*)&lA[row][kg*8] = v;
    }
    // stage B: 256 n-rows x 64 k from Wct [256][512]
#pragma unroll
    for (int i = 0; i < 4; ++i){
      int slot = tid + i*512;
      int n = slot >> 3, kg = slot & 7;
      *(short8*)&lB[n][kg*8] = *(const short8*)(Wct + (size_t)n*K2D + ks*64 + kg*8);
    }
    __syncthreads();
#pragma unroll
    for (int kk = 0; kk < 2; ++kk){
      short8 af[4], bf[4];
#pragma unroll
      for (int f = 0; f < 4; ++f){
        af[f] = *(const short8*)&lA[wm*64 + f*16 + l15][kk*32 + lg*8];
        bf[f] = *(const short8*)&lB[wn*64 + f*16 + l15][kk*32 + lg*8];
      }
#pragma unroll
      for (int fm = 0; fm < 4; ++fm)
#pragma unroll
        for (int fn = 0; fn < 4; ++fn)
          acc[fm][fn] = __builtin_amdgcn_mfma_f32_16x16x32_bf16(af[fm], bf[fn], acc[fm][fn], 0, 0, 0);
    }
  }
#pragma unroll
  for (int fm = 0; fm < 4; ++fm)
#pragma unroll
    for (int fn = 0; fn < 4; ++fn){
      int col = wn*64 + fn*16 + l15;
      float bcv = bc[col];
#pragma unroll
      for (int r = 0; r < 4; ++r){
        int row = rb + wm*64 + fm*16 + lg*4 + r;
        out[(size_t)row*DIM + col] = acc[fm][fn][r] + bcv;
      }
    }
}

extern "C" void kernel_launch(void* const* d_in, const int* in_sizes, int n_in,
                              void* d_out, int out_size, void* d_ws, size_t ws_size,
                              hipStream_t stream){
  const float* feats     = (const float*)d_in[0];
  const int*   cu        = (const int*)d_in[1];
  const int*   layer_ids = (const int*)d_in[2];
  const float* Wa        = (const float*)d_in[3];
  const float* ba        = (const float*)d_in[4];
  const float* W1        = (const float*)d_in[5];
  const float* b1        = (const float*)d_in[6];
  const float* W2        = (const float*)d_in[7];
  const float* b2        = (const float*)d_in[8];
  const float* Wc        = (const float*)d_in[9];
  const float* bc        = (const float*)d_in[10];
  float* out = (float*)d_out;

  char* w = (char*)d_ws;
  auto alloc = [&](size_t bytes)->char*{ char* p = w; w += (bytes + 255) & ~255ull; return p; };
  float*    logits  = (float*)   alloc((size_t)NTOK*4);
  float*    evals   = (float*)   alloc((size_t)NTOK*4);
  int*      seg     = (int*)     alloc((size_t)NTOK*4);
  int*      sorted  = (int*)     alloc((size_t)NTOK*4);
  int*      hist    = (int*)     alloc((size_t)NSEG*HB*4);
  int*      segstart= (int*)     alloc((size_t)(NSEG+1)*4);
  unsigned* bmax    = (unsigned*)alloc(NB*4);
  float*    bz      = (float*)   alloc(NB*4);
  short*    W1t     = (short*)   alloc((size_t)512*768*2);
  short*    W2t     = (short*)   alloc((size_t)256*512*2);
  short*    Wct     = (short*)   alloc((size_t)256*512*2);
  short*    pooledb = (short*)   alloc((size_t)NSEG*K3D*2);
  short*    hb      = (short*)   alloc((size_t)NSEG*EDIM*2);
  short*    lfb     = (short*)   alloc((size_t)NSEG*DIM*2);

  k0_transpose<<<dim3(160), dim3(256), 0, stream>>>(W1, W2, Wc, W1t, W2t, Wct, bmax);
  k1_logits<<<dim3(512), dim3(256), 0, stream>>>(feats, cu, layer_ids, Wa, ba, logits, seg, bmax);
  k2_softmax_z<<<dim3(16), dim3(256), 0, stream>>>(logits, cu, bmax, evals, bz);
  k3a_hist<<<dim3(HB), dim3(256), 0, stream>>>(seg, hist);
  k3b_scan<<<dim3(1), dim3(1024), 0, stream>>>(hist, segstart);
  k3c_scatter<<<dim3(HB), dim3(256), 0, stream>>>(seg, hist, sorted);
  k4_pool<<<dim3(NSEG), dim3(256), 0, stream>>>(feats, sorted, segstart, evals, bz, pooledb);
  gemm64<1><<<dim3(16, 8), dim3(256), 0, stream>>>(pooledb, W1t, b1, hb, 768, 512);
  gemm64<0><<<dim3(16, 4), dim3(256), 0, stream>>>(hb, W2t, b2, lfb, 512, 256);
  k5_final<<<dim3(1024), dim3(512), 0, stream>>>(feats, lfb, seg, Wct, bc, out);
}

// Round 5
// 229.214 us; speedup vs baseline: 1.7511x; 1.0262x over previous
//
#include <hip/hip_runtime.h>
#include <hip/hip_bf16.h>
#include <math.h>

#define NTOK 131072
#define DIM  256
#define EDIM 512
#define NB   16
#define NL   64
#define NSEG (NB*NL)    // 1024
#define K3D  768        // 3*DIM
#define K2D  512        // 2*DIM
#define HB   64         // histogram/scatter blocks (2048 tokens each)

typedef __attribute__((ext_vector_type(8))) short short8;
typedef __attribute__((ext_vector_type(4))) float f32x4;

// monotone float<->uint code so atomicMax(uint) == float max
static __device__ __forceinline__ unsigned fcode(float x){
  unsigned b = __float_as_uint(x);
  return (b & 0x80000000u) ? ~b : (b | 0x80000000u);
}
static __device__ __forceinline__ float fdecode(unsigned c){
  unsigned b = (c & 0x80000000u) ? (c ^ 0x80000000u) : ~c;
  return __uint_as_float(b);
}
#define NEG_INF_CODE 0x007FFFFFu   // fcode(-inf)

static __device__ __forceinline__ short f2bf(float x){
  union { __hip_bfloat16 h; short s; } u; u.h = __float2bfloat16(x); return u.s;
}
static __device__ __forceinline__ float bf2f(short s){
  union { float f; unsigned u; } u; u.u = ((unsigned)(unsigned short)s) << 16; return u.f;
}

// ---------------- K0t: transpose+convert weights to bf16 [N][K]; also init bmax ----------------
__global__ __launch_bounds__(256) void k0_transpose(const float* __restrict__ W1, const float* __restrict__ W2,
                                                    const float* __restrict__ Wc,
                                                    short* __restrict__ W1t, short* __restrict__ W2t,
                                                    short* __restrict__ Wct, unsigned* __restrict__ bmax){
  if (blockIdx.x == 0 && threadIdx.x < NB) bmax[threadIdx.x] = NEG_INF_CODE;
  __shared__ short tile[64][65];
  int b = blockIdx.x;
  const float* src; short* dst; int K, N, kt, nt;
  if (b < 96){ src=W1; dst=W1t; K=768; N=512; kt=b/8;  nt=b%8;  }
  else if (b < 128){ int c=b-96;  src=W2; dst=W2t; K=512; N=256; kt=c/4; nt=c%4; }
  else             { int c=b-128; src=Wc; dst=Wct; K=512; N=256; kt=c/4; nt=c%4; }
  int k0 = kt*64, n0 = nt*64;
  for (int e = threadIdx.x; e < 4096; e += 256){
    int r = e >> 6, c = e & 63;                       // r: k-row, c: n-col (coalesced read)
    tile[c][r] = f2bf(src[(size_t)(k0+r)*N + n0 + c]);
  }
  __syncthreads();
  for (int e = threadIdx.x; e < 4096; e += 256){
    int r = e >> 6, c = e & 63;                       // r: n-row, c: k-col (coalesced write)
    dst[(size_t)(n0+r)*K + k0 + c] = tile[r][c];
  }
}

// ---------------- K1: logits, seg ids, per-batch max (+ optional bf16 feats emit) ----------------
// One thread per token row (GEMV). No cross-lane ops in the hot loop.
template<int WRITEB>
__global__ __launch_bounds__(256) void k1_logits(const float* __restrict__ feats, const int* __restrict__ cu,
    const int* __restrict__ layer_ids, const float* __restrict__ Wa, const float* __restrict__ ba,
    float* __restrict__ logits, int* __restrict__ seg, unsigned* __restrict__ bmax,
    short* __restrict__ featsb){
  __shared__ float4   lwa[64];
  __shared__ int      lcu[NB];
  __shared__ unsigned lbm[NB];
  int tid = threadIdx.x;
  if (tid < 64)  lwa[tid] = *(const float4*)(Wa + tid*4);
  if (tid < NB)  lcu[tid] = cu[tid+1];
  if (tid < NB)  lbm[tid] = NEG_INF_CODE;
  __syncthreads();
  int t = blockIdx.x*256 + tid;
  const float4* fp = (const float4*)(feats + (size_t)t*DIM);
  float a0=0.f, a1=0.f, a2=0.f, a3=0.f;
#pragma unroll
  for (int i = 0; i < 16; ++i){
    float4 x0 = fp[i*4+0], x1 = fp[i*4+1], x2 = fp[i*4+2], x3 = fp[i*4+3];
    float4 w0 = lwa[i*4+0], w1 = lwa[i*4+1], w2 = lwa[i*4+2], w3 = lwa[i*4+3];
    a0 += x0.x*w0.x + x0.y*w0.y + x0.z*w0.z + x0.w*w0.w;
    a1 += x1.x*w1.x + x1.y*w1.y + x1.z*w1.z + x1.w*w1.w;
    a2 += x2.x*w2.x + x2.y*w2.y + x2.z*w2.z + x2.w*w2.w;
    a3 += x3.x*w3.x + x3.y*w3.y + x3.z*w3.z + x3.w*w3.w;
  }
  float lg = (a0+a1) + (a2+a3) + ba[0];
  int b = 0;
#pragma unroll
  for (int j = 0; j < NB-1; ++j) b += (lcu[j] <= t) ? 1 : 0;
  logits[t] = lg;
  seg[t] = b*NL + layer_ids[t];
  atomicMax(&lbm[b], fcode(lg));
  if (WRITEB){
    // re-read this block's 256 rows (L1/L2-hot) and emit bf16, fully coalesced
    int t0 = blockIdx.x*256;
    for (int e = tid; e < 256*32; e += 256){
      int row = e >> 5, g = e & 31;
      const float* fp2 = feats + (size_t)(t0+row)*DIM + g*8;
      float4 u0 = *(const float4*)fp2, u1 = *(const float4*)(fp2+4);
      short8 v;
      v[0]=f2bf(u0.x); v[1]=f2bf(u0.y); v[2]=f2bf(u0.z); v[3]=f2bf(u0.w);
      v[4]=f2bf(u1.x); v[5]=f2bf(u1.y); v[6]=f2bf(u1.z); v[7]=f2bf(u1.w);
      *(short8*)(featsb + (size_t)(t0+row)*DIM + g*8) = v;
    }
  }
  __syncthreads();
  if (tid < NB && lbm[tid] != NEG_INF_CODE) atomicMax(&bmax[tid], lbm[tid]);
}

// ---------------- K2: exp + per-batch Z (deterministic tree) ----------------
__global__ __launch_bounds__(256) void k2_softmax_z(const float* __restrict__ logits, const int* __restrict__ cu,
    const unsigned* __restrict__ bmax, float* __restrict__ evals, float* __restrict__ bz){
  __shared__ float red[256];
  int b = blockIdx.x;
  int s = cu[b], e = cu[b+1];
  float m = fdecode(bmax[b]);
  float acc = 0.f;
  for (int i = s + threadIdx.x; i < e; i += 256){
    float ev = expf(logits[i] - m);
    evals[i] = ev; acc += ev;
  }
  red[threadIdx.x] = acc; __syncthreads();
  for (int off = 128; off; off >>= 1){
    if (threadIdx.x < off) red[threadIdx.x] += red[threadIdx.x + off];
    __syncthreads();
  }
  if (threadIdx.x == 0) bz[b] = red[0];
}

// ---------------- K3a: per-block segment histogram ----------------
__global__ __launch_bounds__(256) void k3a_hist(const int* __restrict__ seg, int* __restrict__ hist){
  __shared__ int h[NSEG];
  for (int i = threadIdx.x; i < NSEG; i += 256) h[i] = 0;
  __syncthreads();
  int base = blockIdx.x * (NTOK/HB);
  for (int i = threadIdx.x; i < NTOK/HB; i += 256) atomicAdd(&h[seg[base+i]], 1);
  __syncthreads();
  for (int i = threadIdx.x; i < NSEG; i += 256) hist[i*HB + blockIdx.x] = h[i];
}

// ---------------- K3b: scan -> per-(seg,block) offsets + segstart ----------------
__global__ __launch_bounds__(1024) void k3b_scan(int* __restrict__ hist, int* __restrict__ segstart){
  __shared__ int sc[NSEG];
  int s = threadIdx.x;
  int base = s*HB;
  int tot = 0;
#pragma unroll
  for (int b = 0; b < HB; ++b) tot += hist[base+b];
  sc[s] = tot; __syncthreads();
  for (int off = 1; off < NSEG; off <<= 1){
    int v = (s >= off) ? sc[s-off] : 0;
    __syncthreads();
    sc[s] += v;
    __syncthreads();
  }
  int segbase = sc[s] - tot;   // exclusive prefix
  segstart[s] = segbase;
  if (s == 0) segstart[NSEG] = NTOK;
  int run = segbase;
#pragma unroll
  for (int b = 0; b < HB; ++b){ int c = hist[base+b]; hist[base+b] = run; run += c; }
}

// ---------------- K3c: stable-ish scatter of token ids by segment ----------------
__global__ __launch_bounds__(256) void k3c_scatter(const int* __restrict__ seg, const int* __restrict__ hist,
                                                   int* __restrict__ sorted){
  __shared__ int cur[NSEG];
  for (int i = threadIdx.x; i < NSEG; i += 256) cur[i] = hist[i*HB + blockIdx.x];
  __syncthreads();
  int base = blockIdx.x * (NTOK/HB);
  for (int i = threadIdx.x; i < NTOK/HB; i += 256){
    int sg = seg[base+i];
    int p = atomicAdd(&cur[sg], 1);
    sorted[p] = base+i;
  }
}

// ---------------- K4: segmented reduce over sorted tokens -> pooled [1024][768] bf16 ----------------
template<int USEB>
__global__ __launch_bounds__(256) void k4_pool(const float* __restrict__ feats, const short* __restrict__ featsb,
    const int* __restrict__ sorted, const int* __restrict__ segstart,
    const float* __restrict__ evals, const float* __restrict__ bz,
    short* __restrict__ pooledb){
  __shared__ float redS[4][DIM];
  __shared__ float redM[4][DIM];
  __shared__ float redA[4][DIM];
  int sgi = blockIdx.x;
  int b = sgi >> 6;
  int s = segstart[sgi], e = segstart[sgi+1];
  int cnt = e - s;
  float invz = 1.0f / bz[b];
  int lane = threadIdx.x & 63, grp = threadIdx.x >> 6;
  float4 sum = make_float4(0.f,0.f,0.f,0.f), att = make_float4(0.f,0.f,0.f,0.f);
  float4 mx  = make_float4(-INFINITY,-INFINITY,-INFINITY,-INFINITY);
  for (int i = s + grp; i < e; i += 4){
    int tok = sorted[i];
    float4 x;
    if (USEB){
      short4 h = *(const short4*)(featsb + (size_t)tok*DIM + lane*4);
      x = make_float4(bf2f(h.x), bf2f(h.y), bf2f(h.z), bf2f(h.w));
    } else {
      x = *(const float4*)(feats + (size_t)tok*DIM + lane*4);
    }
    float w = evals[tok] * invz;
    sum.x += x.x; sum.y += x.y; sum.z += x.z; sum.w += x.w;
    mx.x = fmaxf(mx.x, x.x); mx.y = fmaxf(mx.y, x.y);
    mx.z = fmaxf(mx.z, x.z); mx.w = fmaxf(mx.w, x.w);
    att.x += x.x*w; att.y += x.y*w; att.z += x.z*w; att.w += x.w*w;
  }
  *(float4*)&redS[grp][lane*4] = sum;
  *(float4*)&redM[grp][lane*4] = mx;
  *(float4*)&redA[grp][lane*4] = att;
  __syncthreads();
  int d = threadIdx.x;
  float rs = redS[0][d] + redS[1][d] + redS[2][d] + redS[3][d];
  float rm = fmaxf(fmaxf(redM[0][d], redM[1][d]), fmaxf(redM[2][d], redM[3][d]));
  float ra = redA[0][d] + redA[1][d] + redA[2][d] + redA[3][d];
  float inv = 1.0f / (float)(cnt > 1 ? cnt : 1);
  size_t rb_ = (size_t)sgi * K3D;
  pooledb[rb_ + d]         = f2bf(rs * inv);
  pooledb[rb_ + DIM + d]   = f2bf(cnt > 0 ? rm : 0.f);
  pooledb[rb_ + 2*DIM + d] = f2bf(ra);
}

// ---------------- small MFMA GEMM: C[M,N] = act(A[M,K] @ Bt[N,K]^T + bias) -> bf16 ----------------
template<int GELU>
__global__ __launch_bounds__(256) void gemm64(const short* __restrict__ A, const short* __restrict__ Bt,
    const float* __restrict__ bias, short* __restrict__ Cout, int K, int ldc){
  __shared__ short lA[64][40];
  __shared__ short lB[64][40];
  int tid = threadIdx.x;
  int wave = tid >> 6, lane = tid & 63;
  int wm = wave >> 1, wn = wave & 1;
  int rb = blockIdx.x * 64, cb = blockIdx.y * 64;
  int l15 = lane & 15, lg = lane >> 4;
  f32x4 acc[2][2] = {};
  int srow = tid >> 2, skg = tid & 3;
  for (int ks = 0; ks < K; ks += 32){
    __syncthreads();
    *(short8*)&lA[srow][skg*8] = *(const short8*)(A  + (size_t)(rb+srow)*K + ks + skg*8);
    *(short8*)&lB[srow][skg*8] = *(const short8*)(Bt + (size_t)(cb+srow)*K + ks + skg*8);
    __syncthreads();
    short8 af[2], bf[2];
#pragma unroll
    for (int f = 0; f < 2; ++f){
      af[f] = *(const short8*)&lA[wm*32 + f*16 + l15][lg*8];
      bf[f] = *(const short8*)&lB[wn*32 + f*16 + l15][lg*8];
    }
#pragma unroll
    for (int fm = 0; fm < 2; ++fm)
#pragma unroll
      for (int fn = 0; fn < 2; ++fn)
        acc[fm][fn] = __builtin_amdgcn_mfma_f32_16x16x32_bf16(af[fm], bf[fn], acc[fm][fn], 0, 0, 0);
  }
#pragma unroll
  for (int fm = 0; fm < 2; ++fm)
#pragma unroll
    for (int fn = 0; fn < 2; ++fn){
      int col = cb + wn*32 + fn*16 + l15;
      float bcv = bias[col];
#pragma unroll
      for (int r = 0; r < 4; ++r){
        int row = rb + wm*32 + fm*16 + lg*4 + r;
        float v = acc[fm][fn][r] + bcv;
        if (GELU) v = 0.5f * v * (1.0f + erff(v * 0.70710678118f));
        Cout[(size_t)row*ldc + col] = f2bf(v);
      }
    }
}

// ---------------- K5: out = [gather(lf, seg) | feats] @ Wc + bc ----------------
// 1024 threads = 16 waves (4M x 4N), wave tile 32x64 -> acc[2][4] (32 AGPR).
// Block tile 128 x 256(full N). Double-buffered LDS, prefetch depth 2, 1 barrier/K-step.
template<int USEB>
__global__ __launch_bounds__(1024, 4) void k5_final(const float* __restrict__ feats,
    const short* __restrict__ featsb, const short* __restrict__ lfb,
    const int* __restrict__ seg, const short* __restrict__ Wct, const float* __restrict__ bc,
    float* __restrict__ out){
  __shared__ short lA[2][128][72];
  __shared__ short lB[2][256][72];
  int tid = threadIdx.x;
  int wave = tid >> 6, lane = tid & 63;
  int wm = wave >> 2, wn = wave & 3;
  int bid = (int)blockIdx.x;
  int swz = (bid & 7) * 128 + (bid >> 3);     // XCD-aware, bijective (1024 % 8 == 0)
  int rb = swz * 128;
  int l15 = lane & 15, lg = lane >> 4;
  // staging slots: A = 128 rows x 8 kgroups (1 per thread); B = 256 rows x 8 kgroups (2 per thread)
  int arow = tid >> 3, akg = tid & 7;
  int brow0 = tid >> 3, brow1 = (tid + 1024) >> 3, bkg = tid & 7;
  const short* lfbp = lfb + (size_t)seg[rb + arow]*DIM + akg*8;   // hoisted gather
  const short* fbp  = featsb + (size_t)(rb + arow)*DIM + akg*8;
  const float* ffp  = feats  + (size_t)(rb + arow)*DIM + akg*8;
  const short* wp0 = Wct + (size_t)brow0*K2D + bkg*8;
  const short* wp1 = Wct + (size_t)brow1*K2D + bkg*8;
  short8 ra, rb0, rb1; float4 fa0, fa1;
  auto LOAD = [&](int t){
    if (t < 4)      ra = *(const short8*)(lfbp + t*64);
    else if (USEB)  ra = *(const short8*)(fbp + (t-4)*64);
    else { const float* p = ffp + (size_t)(t-4)*64; fa0 = *(const float4*)p; fa1 = *(const float4*)(p+4); }
    rb0 = *(const short8*)(wp0 + t*64);
    rb1 = *(const short8*)(wp1 + t*64);
  };
  auto WRITE = [&](int t){
    int buf = t & 1;
    if (!USEB && t >= 4){
      short8 v;
      v[0]=f2bf(fa0.x); v[1]=f2bf(fa0.y); v[2]=f2bf(fa0.z); v[3]=f2bf(fa0.w);
      v[4]=f2bf(fa1.x); v[5]=f2bf(fa1.y); v[6]=f2bf(fa1.z); v[7]=f2bf(fa1.w);
      *(short8*)&lA[buf][arow][akg*8] = v;
    } else {
      *(short8*)&lA[buf][arow][akg*8] = ra;
    }
    *(short8*)&lB[buf][brow0][bkg*8] = rb0;
    *(short8*)&lB[buf][brow1][bkg*8] = rb1;
  };
  f32x4 acc[2][4] = {};
  LOAD(0); WRITE(0); LOAD(1);
  __syncthreads();
  for (int ks = 0; ks < 8; ++ks){
    int cur = ks & 1;
    if (ks < 7) WRITE(ks+1);        // into buf[cur^1]; safe: consumed at ks-1, barrier passed
    if (ks < 6) LOAD(ks+2);         // issue early; lands under this phase's compute
#pragma unroll
    for (int kk = 0; kk < 2; ++kk){
      short8 af[2], bf[4];
#pragma unroll
      for (int f = 0; f < 2; ++f)
        af[f] = *(const short8*)&lA[cur][wm*32 + f*16 + l15][kk*32 + lg*8];
#pragma unroll
      for (int f = 0; f < 4; ++f)
        bf[f] = *(const short8*)&lB[cur][wn*64 + f*16 + l15][kk*32 + lg*8];
#pragma unroll
      for (int fm = 0; fm < 2; ++fm)
#pragma unroll
        for (int fn = 0; fn < 4; ++fn)
          acc[fm][fn] = __builtin_amdgcn_mfma_f32_16x16x32_bf16(af[fm], bf[fn], acc[fm][fn], 0, 0, 0);
    }
    __syncthreads();
  }
#pragma unroll
  for (int fm = 0; fm < 2; ++fm)
#pragma unroll
    for (int fn = 0; fn < 4; ++fn){
      int col = wn*64 + fn*16 + l15;
      float bcv = bc[col];
#pragma unroll
      for (int r = 0; r < 4; ++r){
        int row = rb + wm*32 + fm*16 + lg*4 + r;
        out[(size_t)row*DIM + col] = acc[fm][fn][r] + bcv;
      }
    }
}

extern "C" void kernel_launch(void* const* d_in, const int* in_sizes, int n_in,
                              void* d_out, int out_size, void* d_ws, size_t ws_size,
                              hipStream_t stream){
  const float* feats     = (const float*)d_in[0];
  const int*   cu        = (const int*)d_in[1];
  const int*   layer_ids = (const int*)d_in[2];
  const float* Wa        = (const float*)d_in[3];
  const float* ba        = (const float*)d_in[4];
  const float* W1        = (const float*)d_in[5];
  const float* b1        = (const float*)d_in[6];
  const float* W2        = (const float*)d_in[7];
  const float* b2        = (const float*)d_in[8];
  const float* Wc        = (const float*)d_in[9];
  const float* bc        = (const float*)d_in[10];
  float* out = (float*)d_out;

  char* w = (char*)d_ws;
  auto alloc = [&](size_t bytes)->char*{ char* p = w; w += (bytes + 255) & ~255ull; return p; };
  float*    logits  = (float*)   alloc((size_t)NTOK*4);
  float*    evals   = (float*)   alloc((size_t)NTOK*4);
  int*      seg     = (int*)     alloc((size_t)NTOK*4);
  int*      sorted  = (int*)     alloc((size_t)NTOK*4);
  int*      hist    = (int*)     alloc((size_t)NSEG*HB*4);
  int*      segstart= (int*)     alloc((size_t)(NSEG+1)*4);
  unsigned* bmax    = (unsigned*)alloc(NB*4);
  float*    bz      = (float*)   alloc(NB*4);
  short*    W1t     = (short*)   alloc((size_t)512*768*2);
  short*    W2t     = (short*)   alloc((size_t)256*512*2);
  short*    Wct     = (short*)   alloc((size_t)256*512*2);
  short*    pooledb = (short*)   alloc((size_t)NSEG*K3D*2);
  short*    hb      = (short*)   alloc((size_t)NSEG*EDIM*2);
  short*    lfb     = (short*)   alloc((size_t)NSEG*DIM*2);
  short*    featsb  = (short*)   alloc((size_t)NTOK*DIM*2);     // 67 MB, gated
  size_t need = (size_t)(w - (char*)d_ws);
  bool useb = (ws_size >= need);

  k0_transpose<<<dim3(160), dim3(256), 0, stream>>>(W1, W2, Wc, W1t, W2t, Wct, bmax);
  if (useb)
    k1_logits<1><<<dim3(512), dim3(256), 0, stream>>>(feats, cu, layer_ids, Wa, ba, logits, seg, bmax, featsb);
  else
    k1_logits<0><<<dim3(512), dim3(256), 0, stream>>>(feats, cu, layer_ids, Wa, ba, logits, seg, bmax, featsb);
  k2_softmax_z<<<dim3(16), dim3(256), 0, stream>>>(logits, cu, bmax, evals, bz);
  k3a_hist<<<dim3(HB), dim3(256), 0, stream>>>(seg, hist);
  k3b_scan<<<dim3(1), dim3(1024), 0, stream>>>(hist, segstart);
  k3c_scatter<<<dim3(HB), dim3(256), 0, stream>>>(seg, hist, sorted);
  if (useb)
    k4_pool<1><<<dim3(NSEG), dim3(256), 0, stream>>>(feats, featsb, sorted, segstart, evals, bz, pooledb);
  else
    k4_pool<0><<<dim3(NSEG), dim3(256), 0, stream>>>(feats, featsb, sorted, segstart, evals, bz, pooledb);
  gemm64<1><<<dim3(16, 8), dim3(256), 0, stream>>>(pooledb, W1t, b1, hb, 768, 512);
  gemm64<0><<<dim3(16, 4), dim3(256), 0, stream>>>(hb, W2t, b2, lfb, 512, 256);
  if (useb)
    k5_final<1><<<dim3(1024), dim3(1024), 0, stream>>>(feats, featsb, lfb, seg, Wct, bc, out);
  else
    k5_final<0><<<dim3(1024), dim3(1024), 0, stream>>>(feats, featsb, lfb, seg, Wct, bc, out);
}

// Round 6
// 226.028 us; speedup vs baseline: 1.7758x; 1.0141x over previous
//
#include <hip/hip_runtime.h>
#include <hip/hip_bf16.h>
#include <math.h>

#define NTOK 131072
#define DIM  256
#define EDIM 512
#define NB   16
#define NL   64
#define NSEG (NB*NL)    // 1024
#define K3D  768        // 3*DIM
#define K2D  512        // 2*DIM
#define HB   64         // histogram/scatter blocks (2048 tokens each)

typedef __attribute__((ext_vector_type(8))) short short8;
typedef __attribute__((ext_vector_type(4))) float f32x4;

// monotone float<->uint code so atomicMax(uint) == float max
static __device__ __forceinline__ unsigned fcode(float x){
  unsigned b = __float_as_uint(x);
  return (b & 0x80000000u) ? ~b : (b | 0x80000000u);
}
static __device__ __forceinline__ float fdecode(unsigned c){
  unsigned b = (c & 0x80000000u) ? (c ^ 0x80000000u) : ~c;
  return __uint_as_float(b);
}
#define NEG_INF_CODE 0x007FFFFFu   // fcode(-inf)

static __device__ __forceinline__ short f2bf(float x){
  union { __hip_bfloat16 h; short s; } u; u.h = __float2bfloat16(x); return u.s;
}
static __device__ __forceinline__ float bf2f(short s){
  union { float f; unsigned u; } u; u.u = ((unsigned)(unsigned short)s) << 16; return u.f;
}

// ---------------- K0t: transpose+convert weights to bf16 [N][K]; also init bmax ----------------
__global__ __launch_bounds__(256) void k0_transpose(const float* __restrict__ W1, const float* __restrict__ W2,
                                                    const float* __restrict__ Wc,
                                                    short* __restrict__ W1t, short* __restrict__ W2t,
                                                    short* __restrict__ Wct, unsigned* __restrict__ bmax){
  if (blockIdx.x == 0 && threadIdx.x < NB) bmax[threadIdx.x] = NEG_INF_CODE;
  __shared__ short tile[64][65];
  int b = blockIdx.x;
  const float* src; short* dst; int K, N, kt, nt;
  if (b < 96){ src=W1; dst=W1t; K=768; N=512; kt=b/8;  nt=b%8;  }
  else if (b < 128){ int c=b-96;  src=W2; dst=W2t; K=512; N=256; kt=c/4; nt=c%4; }
  else             { int c=b-128; src=Wc; dst=Wct; K=512; N=256; kt=c/4; nt=c%4; }
  int k0 = kt*64, n0 = nt*64;
  for (int e = threadIdx.x; e < 4096; e += 256){
    int r = e >> 6, c = e & 63;                       // r: k-row, c: n-col (coalesced read)
    tile[c][r] = f2bf(src[(size_t)(k0+r)*N + n0 + c]);
  }
  __syncthreads();
  for (int e = threadIdx.x; e < 4096; e += 256){
    int r = e >> 6, c = e & 63;                       // r: n-row, c: k-col (coalesced write)
    dst[(size_t)(n0+r)*K + k0 + c] = tile[r][c];
  }
}

// ---------------- K1 v3: logits + seg + per-batch max + bf16 emit, 4 lanes per row ----------------
// 524288 threads = 8192 waves = full chip. Each lane owns a contiguous 64-float quarter-row:
// 4 x 64B line loads, FMA, bf16 convert+store from registers (no re-read). Two shfl_xor after
// the loop only (post-loop cross-lane is cheap; in-loop was the round-3 regression).
template<int WRITEB>
__global__ __launch_bounds__(256) void k1_logits(const float* __restrict__ feats, const int* __restrict__ cu,
    const int* __restrict__ layer_ids, const float* __restrict__ Wa, const float* __restrict__ ba,
    float* __restrict__ logits, int* __restrict__ seg, unsigned* __restrict__ bmax,
    short* __restrict__ featsb){
  __shared__ float4   lwa[64];
  __shared__ int      lcu[NB];
  __shared__ unsigned lbm[NB];
  int tid = threadIdx.x;
  if (tid < 64)  lwa[tid] = *(const float4*)(Wa + tid*4);
  if (tid < NB){ lcu[tid] = cu[tid+1]; lbm[tid] = NEG_INF_CODE; }
  __syncthreads();
  int q = tid & 3;                       // quarter within row
  int r = blockIdx.x*64 + (tid >> 2);    // token row
  const float4* fp = (const float4*)(feats + (size_t)r*DIM + q*64);
  short8* ob = (short8*)(featsb + (size_t)r*DIM + q*64);
  float a0 = 0.f, a1 = 0.f;
#pragma unroll
  for (int i = 0; i < 4; ++i){
    float4 x0 = fp[i*4+0], x1 = fp[i*4+1], x2 = fp[i*4+2], x3 = fp[i*4+3];
    float4 w0 = lwa[q*16+i*4+0], w1 = lwa[q*16+i*4+1], w2 = lwa[q*16+i*4+2], w3 = lwa[q*16+i*4+3];
    a0 += x0.x*w0.x + x0.y*w0.y + x0.z*w0.z + x0.w*w0.w
        + x2.x*w2.x + x2.y*w2.y + x2.z*w2.z + x2.w*w2.w;
    a1 += x1.x*w1.x + x1.y*w1.y + x1.z*w1.z + x1.w*w1.w
        + x3.x*w3.x + x3.y*w3.y + x3.z*w3.z + x3.w*w3.w;
    if (WRITEB){
      short8 v0, v1;
      v0[0]=f2bf(x0.x); v0[1]=f2bf(x0.y); v0[2]=f2bf(x0.z); v0[3]=f2bf(x0.w);
      v0[4]=f2bf(x1.x); v0[5]=f2bf(x1.y); v0[6]=f2bf(x1.z); v0[7]=f2bf(x1.w);
      v1[0]=f2bf(x2.x); v1[1]=f2bf(x2.y); v1[2]=f2bf(x2.z); v1[3]=f2bf(x2.w);
      v1[4]=f2bf(x3.x); v1[5]=f2bf(x3.y); v1[6]=f2bf(x3.z); v1[7]=f2bf(x3.w);
      ob[i*2]   = v0;
      ob[i*2+1] = v1;
    }
  }
  float p = a0 + a1;
  p += __shfl_xor(p, 1);
  p += __shfl_xor(p, 2);
  if (q == 0){
    float lg = p + ba[0];
    logits[r] = lg;
    int b = 0;
#pragma unroll
    for (int j = 0; j < NB-1; ++j) b += (lcu[j] <= r) ? 1 : 0;
    seg[r] = b*NL + layer_ids[r];
    atomicMax(&lbm[b], fcode(lg));
  }
  __syncthreads();
  if (tid < NB && lbm[tid] != NEG_INF_CODE) atomicMax(&bmax[tid], lbm[tid]);
}

// ---------------- K2: exp + per-batch Z (deterministic tree) ----------------
__global__ __launch_bounds__(256) void k2_softmax_z(const float* __restrict__ logits, const int* __restrict__ cu,
    const unsigned* __restrict__ bmax, float* __restrict__ evals, float* __restrict__ bz){
  __shared__ float red[256];
  int b = blockIdx.x;
  int s = cu[b], e = cu[b+1];
  float m = fdecode(bmax[b]);
  float acc = 0.f;
  for (int i = s + threadIdx.x; i < e; i += 256){
    float ev = expf(logits[i] - m);
    evals[i] = ev; acc += ev;
  }
  red[threadIdx.x] = acc; __syncthreads();
  for (int off = 128; off; off >>= 1){
    if (threadIdx.x < off) red[threadIdx.x] += red[threadIdx.x + off];
    __syncthreads();
  }
  if (threadIdx.x == 0) bz[b] = red[0];
}

// ---------------- K3a: per-block segment histogram ----------------
__global__ __launch_bounds__(256) void k3a_hist(const int* __restrict__ seg, int* __restrict__ hist){
  __shared__ int h[NSEG];
  for (int i = threadIdx.x; i < NSEG; i += 256) h[i] = 0;
  __syncthreads();
  int base = blockIdx.x * (NTOK/HB);
  for (int i = threadIdx.x; i < NTOK/HB; i += 256) atomicAdd(&h[seg[base+i]], 1);
  __syncthreads();
  for (int i = threadIdx.x; i < NSEG; i += 256) hist[i*HB + blockIdx.x] = h[i];
}

// ---------------- K3b: scan -> per-(seg,block) offsets + segstart ----------------
__global__ __launch_bounds__(1024) void k3b_scan(int* __restrict__ hist, int* __restrict__ segstart){
  __shared__ int sc[NSEG];
  int s = threadIdx.x;
  int base = s*HB;
  int tot = 0;
#pragma unroll
  for (int b = 0; b < HB; ++b) tot += hist[base+b];
  sc[s] = tot; __syncthreads();
  for (int off = 1; off < NSEG; off <<= 1){
    int v = (s >= off) ? sc[s-off] : 0;
    __syncthreads();
    sc[s] += v;
    __syncthreads();
  }
  int segbase = sc[s] - tot;   // exclusive prefix
  segstart[s] = segbase;
  if (s == 0) segstart[NSEG] = NTOK;
  int run = segbase;
#pragma unroll
  for (int b = 0; b < HB; ++b){ int c = hist[base+b]; hist[base+b] = run; run += c; }
}

// ---------------- K3c: stable-ish scatter of token ids by segment ----------------
__global__ __launch_bounds__(256) void k3c_scatter(const int* __restrict__ seg, const int* __restrict__ hist,
                                                   int* __restrict__ sorted){
  __shared__ int cur[NSEG];
  for (int i = threadIdx.x; i < NSEG; i += 256) cur[i] = hist[i*HB + blockIdx.x];
  __syncthreads();
  int base = blockIdx.x * (NTOK/HB);
  for (int i = threadIdx.x; i < NTOK/HB; i += 256){
    int sg = seg[base+i];
    int p = atomicAdd(&cur[sg], 1);
    sorted[p] = base+i;
  }
}

// ---------------- K4: segmented reduce over sorted tokens -> pooled [1024][768] bf16 ----------------
template<int USEB>
__global__ __launch_bounds__(256) void k4_pool(const float* __restrict__ feats, const short* __restrict__ featsb,
    const int* __restrict__ sorted, const int* __restrict__ segstart,
    const float* __restrict__ evals, const float* __restrict__ bz,
    short* __restrict__ pooledb){
  __shared__ float redS[4][DIM];
  __shared__ float redM[4][DIM];
  __shared__ float redA[4][DIM];
  int sgi = blockIdx.x;
  int b = sgi >> 6;
  int s = segstart[sgi], e = segstart[sgi+1];
  int cnt = e - s;
  float invz = 1.0f / bz[b];
  int lane = threadIdx.x & 63, grp = threadIdx.x >> 6;
  float4 sum = make_float4(0.f,0.f,0.f,0.f), att = make_float4(0.f,0.f,0.f,0.f);
  float4 mx  = make_float4(-INFINITY,-INFINITY,-INFINITY,-INFINITY);
  for (int i = s + grp; i < e; i += 4){
    int tok = sorted[i];
    float4 x;
    if (USEB){
      short4 h = *(const short4*)(featsb + (size_t)tok*DIM + lane*4);
      x = make_float4(bf2f(h.x), bf2f(h.y), bf2f(h.z), bf2f(h.w));
    } else {
      x = *(const float4*)(feats + (size_t)tok*DIM + lane*4);
    }
    float w = evals[tok] * invz;
    sum.x += x.x; sum.y += x.y; sum.z += x.z; sum.w += x.w;
    mx.x = fmaxf(mx.x, x.x); mx.y = fmaxf(mx.y, x.y);
    mx.z = fmaxf(mx.z, x.z); mx.w = fmaxf(mx.w, x.w);
    att.x += x.x*w; att.y += x.y*w; att.z += x.z*w; att.w += x.w*w;
  }
  *(float4*)&redS[grp][lane*4] = sum;
  *(float4*)&redM[grp][lane*4] = mx;
  *(float4*)&redA[grp][lane*4] = att;
  __syncthreads();
  int d = threadIdx.x;
  float rs = redS[0][d] + redS[1][d] + redS[2][d] + redS[3][d];
  float rm = fmaxf(fmaxf(redM[0][d], redM[1][d]), fmaxf(redM[2][d], redM[3][d]));
  float ra = redA[0][d] + redA[1][d] + redA[2][d] + redA[3][d];
  float inv = 1.0f / (float)(cnt > 1 ? cnt : 1);
  size_t rb_ = (size_t)sgi * K3D;
  pooledb[rb_ + d]         = f2bf(rs * inv);
  pooledb[rb_ + DIM + d]   = f2bf(cnt > 0 ? rm : 0.f);
  pooledb[rb_ + 2*DIM + d] = f2bf(ra);
}

// ---------------- small MFMA GEMM: C[M,N] = act(A[M,K] @ Bt[N,K]^T + bias) -> bf16 ----------------
template<int GELU>
__global__ __launch_bounds__(256) void gemm64(const short* __restrict__ A, const short* __restrict__ Bt,
    const float* __restrict__ bias, short* __restrict__ Cout, int K, int ldc){
  __shared__ short lA[64][40];
  __shared__ short lB[64][40];
  int tid = threadIdx.x;
  int wave = tid >> 6, lane = tid & 63;
  int wm = wave >> 1, wn = wave & 1;
  int rb = blockIdx.x * 64, cb = blockIdx.y * 64;
  int l15 = lane & 15, lg = lane >> 4;
  f32x4 acc[2][2] = {};
  int srow = tid >> 2, skg = tid & 3;
  for (int ks = 0; ks < K; ks += 32){
    __syncthreads();
    *(short8*)&lA[srow][skg*8] = *(const short8*)(A  + (size_t)(rb+srow)*K + ks + skg*8);
    *(short8*)&lB[srow][skg*8] = *(const short8*)(Bt + (size_t)(cb+srow)*K + ks + skg*8);
    __syncthreads();
    short8 af[2], bf[2];
#pragma unroll
    for (int f = 0; f < 2; ++f){
      af[f] = *(const short8*)&lA[wm*32 + f*16 + l15][lg*8];
      bf[f] = *(const short8*)&lB[wn*32 + f*16 + l15][lg*8];
    }
#pragma unroll
    for (int fm = 0; fm < 2; ++fm)
#pragma unroll
      for (int fn = 0; fn < 2; ++fn)
        acc[fm][fn] = __builtin_amdgcn_mfma_f32_16x16x32_bf16(af[fm], bf[fn], acc[fm][fn], 0, 0, 0);
  }
#pragma unroll
  for (int fm = 0; fm < 2; ++fm)
#pragma unroll
    for (int fn = 0; fn < 2; ++fn){
      int col = cb + wn*32 + fn*16 + l15;
      float bcv = bias[col];
#pragma unroll
      for (int r = 0; r < 4; ++r){
        int row = rb + wm*32 + fm*16 + lg*4 + r;
        float v = acc[fm][fn][r] + bcv;
        if (GELU) v = 0.5f * v * (1.0f + erff(v * 0.70710678118f));
        Cout[(size_t)row*ldc + col] = f2bf(v);
      }
    }
}

// ---------------- K5: out = [gather(lf, seg) | feats] @ Wc + bc ----------------
// 1024 threads = 16 waves (4M x 4N), wave tile 32x64 -> acc[2][4] (32 AGPR).
// Block tile 128 x 256(full N). Double-buffered LDS, prefetch depth 2, 1 barrier/K-step.
template<int USEB>
__global__ __launch_bounds__(1024, 4) void k5_final(const float* __restrict__ feats,
    const short* __restrict__ featsb, const short* __restrict__ lfb,
    const int* __restrict__ seg, const short* __restrict__ Wct, const float* __restrict__ bc,
    float* __restrict__ out){
  __shared__ short lA[2][128][72];
  __shared__ short lB[2][256][72];
  int tid = threadIdx.x;
  int wave = tid >> 6, lane = tid & 63;
  int wm = wave >> 2, wn = wave & 3;
  int bid = (int)blockIdx.x;
  int swz = (bid & 7) * 128 + (bid >> 3);     // XCD-aware, bijective (1024 % 8 == 0)
  int rb = swz * 128;
  int l15 = lane & 15, lg = lane >> 4;
  // staging slots: A = 128 rows x 8 kgroups (1 per thread); B = 256 rows x 8 kgroups (2 per thread)
  int arow = tid >> 3, akg = tid & 7;
  int brow0 = tid >> 3, brow1 = (tid + 1024) >> 3, bkg = tid & 7;
  const short* lfbp = lfb + (size_t)seg[rb + arow]*DIM + akg*8;   // hoisted gather
  const short* fbp  = featsb + (size_t)(rb + arow)*DIM + akg*8;
  const float* ffp  = feats  + (size_t)(rb + arow)*DIM + akg*8;
  const short* wp0 = Wct + (size_t)brow0*K2D + bkg*8;
  const short* wp1 = Wct + (size_t)brow1*K2D + bkg*8;
  short8 ra, rb0, rb1; float4 fa0, fa1;
  auto LOAD = [&](int t){
    if (t < 4)      ra = *(const short8*)(lfbp + t*64);
    else if (USEB)  ra = *(const short8*)(fbp + (t-4)*64);
    else { const float* p = ffp + (size_t)(t-4)*64; fa0 = *(const float4*)p; fa1 = *(const float4*)(p+4); }
    rb0 = *(const short8*)(wp0 + t*64);
    rb1 = *(const short8*)(wp1 + t*64);
  };
  auto WRITE = [&](int t){
    int buf = t & 1;
    if (!USEB && t >= 4){
      short8 v;
      v[0]=f2bf(fa0.x); v[1]=f2bf(fa0.y); v[2]=f2bf(fa0.z); v[3]=f2bf(fa0.w);
      v[4]=f2bf(fa1.x); v[5]=f2bf(fa1.y); v[6]=f2bf(fa1.z); v[7]=f2bf(fa1.w);
      *(short8*)&lA[buf][arow][akg*8] = v;
    } else {
      *(short8*)&lA[buf][arow][akg*8] = ra;
    }
    *(short8*)&lB[buf][brow0][bkg*8] = rb0;
    *(short8*)&lB[buf][brow1][bkg*8] = rb1;
  };
  f32x4 acc[2][4] = {};
  LOAD(0); WRITE(0); LOAD(1);
  __syncthreads();
  for (int ks = 0; ks < 8; ++ks){
    int cur = ks & 1;
    if (ks < 7) WRITE(ks+1);        // into buf[cur^1]; safe: consumed at ks-1, barrier passed
    if (ks < 6) LOAD(ks+2);         // issue early; lands under this phase's compute
#pragma unroll
    for (int kk = 0; kk < 2; ++kk){
      short8 af[2], bf[4];
#pragma unroll
      for (int f = 0; f < 2; ++f)
        af[f] = *(const short8*)&lA[cur][wm*32 + f*16 + l15][kk*32 + lg*8];
#pragma unroll
      for (int f = 0; f < 4; ++f)
        bf[f] = *(const short8*)&lB[cur][wn*64 + f*16 + l15][kk*32 + lg*8];
#pragma unroll
      for (int fm = 0; fm < 2; ++fm)
#pragma unroll
        for (int fn = 0; fn < 4; ++fn)
          acc[fm][fn] = __builtin_amdgcn_mfma_f32_16x16x32_bf16(af[fm], bf[fn], acc[fm][fn], 0, 0, 0);
    }
    __syncthreads();
  }
#pragma unroll
  for (int fm = 0; fm < 2; ++fm)
#pragma unroll
    for (int fn = 0; fn < 4; ++fn){
      int col = wn*64 + fn*16 + l15;
      float bcv = bc[col];
#pragma unroll
      for (int r = 0; r < 4; ++r){
        int row = rb + wm*32 + fm*16 + lg*4 + r;
        out[(size_t)row*DIM + col] = acc[fm][fn][r] + bcv;
      }
    }
}

extern "C" void kernel_launch(void* const* d_in, const int* in_sizes, int n_in,
                              void* d_out, int out_size, void* d_ws, size_t ws_size,
                              hipStream_t stream){
  const float* feats     = (const float*)d_in[0];
  const int*   cu        = (const int*)d_in[1];
  const int*   layer_ids = (const int*)d_in[2];
  const float* Wa        = (const float*)d_in[3];
  const float* ba        = (const float*)d_in[4];
  const float* W1        = (const float*)d_in[5];
  const float* b1        = (const float*)d_in[6];
  const float* W2        = (const float*)d_in[7];
  const float* b2        = (const float*)d_in[8];
  const float* Wc        = (const float*)d_in[9];
  const float* bc        = (const float*)d_in[10];
  float* out = (float*)d_out;

  char* w = (char*)d_ws;
  auto alloc = [&](size_t bytes)->char*{ char* p = w; w += (bytes + 255) & ~255ull; return p; };
  float*    logits  = (float*)   alloc((size_t)NTOK*4);
  float*    evals   = (float*)   alloc((size_t)NTOK*4);
  int*      seg     = (int*)     alloc((size_t)NTOK*4);
  int*      sorted  = (int*)     alloc((size_t)NTOK*4);
  int*      hist    = (int*)     alloc((size_t)NSEG*HB*4);
  int*      segstart= (int*)     alloc((size_t)(NSEG+1)*4);
  unsigned* bmax    = (unsigned*)alloc(NB*4);
  float*    bz      = (float*)   alloc(NB*4);
  short*    W1t     = (short*)   alloc((size_t)512*768*2);
  short*    W2t     = (short*)   alloc((size_t)256*512*2);
  short*    Wct     = (short*)   alloc((size_t)256*512*2);
  short*    pooledb = (short*)   alloc((size_t)NSEG*K3D*2);
  short*    hb      = (short*)   alloc((size_t)NSEG*EDIM*2);
  short*    lfb     = (short*)   alloc((size_t)NSEG*DIM*2);
  short*    featsb  = (short*)   alloc((size_t)NTOK*DIM*2);     // 67 MB, gated
  size_t need = (size_t)(w - (char*)d_ws);
  bool useb = (ws_size >= need);

  k0_transpose<<<dim3(160), dim3(256), 0, stream>>>(W1, W2, Wc, W1t, W2t, Wct, bmax);
  if (useb)
    k1_logits<1><<<dim3(2048), dim3(256), 0, stream>>>(feats, cu, layer_ids, Wa, ba, logits, seg, bmax, featsb);
  else
    k1_logits<0><<<dim3(2048), dim3(256), 0, stream>>>(feats, cu, layer_ids, Wa, ba, logits, seg, bmax, featsb);
  k2_softmax_z<<<dim3(16), dim3(256), 0, stream>>>(logits, cu, bmax, evals, bz);
  k3a_hist<<<dim3(HB), dim3(256), 0, stream>>>(seg, hist);
  k3b_scan<<<dim3(1), dim3(1024), 0, stream>>>(hist, segstart);
  k3c_scatter<<<dim3(HB), dim3(256), 0, stream>>>(seg, hist, sorted);
  if (useb)
    k4_pool<1><<<dim3(NSEG), dim3(256), 0, stream>>>(feats, featsb, sorted, segstart, evals, bz, pooledb);
  else
    k4_pool<0><<<dim3(NSEG), dim3(256), 0, stream>>>(feats, featsb, sorted, segstart, evals, bz, pooledb);
  gemm64<1><<<dim3(16, 8), dim3(256), 0, stream>>>(pooledb, W1t, b1, hb, 768, 512);
  gemm64<0><<<dim3(16, 4), dim3(256), 0, stream>>>(hb, W2t, b2, lfb, 512, 256);
  if (useb)
    k5_final<1><<<dim3(1024), dim3(1024), 0, stream>>>(feats, featsb, lfb, seg, Wct, bc, out);
  else
    k5_final<0><<<dim3(1024), dim3(1024), 0, stream>>>(feats, featsb, lfb, seg, Wct, bc, out);
}